// Round 7
// baseline (244.810 us; speedup 1.0000x reference)
//
#include <hip/hip_runtime.h>

#define NN 100000
#define BN_EPS 1e-5f
#define NB 391          // buckets = ceil(NN/256), bucket b owns cols [b*256, b*256+256)
#define CAP 5120        // per-bucket edge capacity
#define TILE 4096       // edges per k_bin block

#define CVT_BLKS 6250   // NN*16 float4s / 256
#define ZERO_BLKS 33    // 8192 bcur + 256 stats = 8448 ints
#define PACK1_BLKS 32   // 64*128 / 256

typedef __attribute__((ext_vector_type(4))) _Float16 half4;
typedef __attribute__((ext_vector_type(8))) _Float16 half8;
typedef __attribute__((ext_vector_type(4))) float f32x4;

// ---------------- pass 1: bin edges by col>>8, bucket-sorted coalesced writes ----------------

__global__ __launch_bounds__(256) void k_bin(const int* __restrict__ row,
                                             const int* __restrict__ col,
                                             int* __restrict__ bcur,   // NB counters, stride 16
                                             int* __restrict__ ebuf,   // NB*CAP packed edges
                                             int E) {
    __shared__ int hist[512];
    __shared__ int excl[512];
    __shared__ int cur[512];
    __shared__ int gbase[512];
    __shared__ int sc[256];
    __shared__ int staged[TILE];
    __shared__ unsigned short bkt[TILE];
    const int t = threadIdx.x;
    const int base = blockIdx.x * TILE;
    const int nE = min(TILE, E - base);

    hist[t] = 0; hist[t + 256] = 0;
    cur[t] = 0;  cur[t + 256] = 0;
    __syncthreads();

    int er[16], ec[16];
    #pragma unroll
    for (int k = 0; k < 16; ++k) {
        int idx = base + k * 256 + t;
        if (idx < E) {
            er[k] = row[idx];
            ec[k] = col[idx];
            atomicAdd(&hist[ec[k] >> 8], 1);
        } else {
            ec[k] = -1;
        }
    }
    __syncthreads();

    int p = hist[2 * t] + hist[2 * t + 1];
    sc[t] = p;
    __syncthreads();
    for (int off = 1; off < 256; off <<= 1) {
        int add = (t >= off) ? sc[t - off] : 0;
        __syncthreads();
        sc[t] += add;
        __syncthreads();
    }
    int P = sc[t];
    excl[2 * t]     = P - p;
    excl[2 * t + 1] = P - p + hist[2 * t];
    __syncthreads();

    for (int b = t; b < NB; b += 256) {
        int h = hist[b];
        gbase[b] = h ? atomicAdd(&bcur[b * 16], h) : 0;
    }

    #pragma unroll
    for (int k = 0; k < 16; ++k) {
        int c = ec[k];
        if (c < 0) continue;
        int b = c >> 8;
        int slot = excl[b] + atomicAdd(&cur[b], 1);
        staged[slot] = (er[k] << 8) | (c & 255);
        bkt[slot] = (unsigned short)b;
    }
    __syncthreads();

    for (int i = t; i < nE; i += 256) {
        int b = bkt[i];
        int off = gbase[b] + (i - excl[b]);
        if (off < CAP) ebuf[b * CAP + off] = staged[i];
    }
}

// ---------------- pass 2: per-bucket CSR finalize ----------------

__global__ __launch_bounds__(256) void k_csr(const int* __restrict__ bcur,
                                             const int* __restrict__ ebuf,
                                             int* __restrict__ rows,
                                             int* __restrict__ start,
                                             int* __restrict__ cnt,
                                             float* __restrict__ dis) {
    __shared__ int hist[256];
    __shared__ int lstart[256];
    __shared__ int cur[256];
    __shared__ int sc[256];
    const int b = blockIdx.x;
    const int t = threadIdx.x;
    const int fill = min(bcur[b * 16], CAP);

    hist[t] = 0; cur[t] = 0;
    __syncthreads();

    int er[CAP / 256];
    #pragma unroll
    for (int k = 0; k < CAP / 256; ++k) {
        int i = k * 256 + t;
        if (i < fill) {
            er[k] = ebuf[b * CAP + i];
            atomicAdd(&hist[er[k] & 255], 1);
        }
    }
    __syncthreads();

    int v = hist[t];
    sc[t] = v;
    __syncthreads();
    for (int off = 1; off < 256; off <<= 1) {
        int add = (t >= off) ? sc[t - off] : 0;
        __syncthreads();
        sc[t] += add;
        __syncthreads();
    }
    lstart[t] = sc[t] - v;

    const int node = b * 256 + t;
    if (node < NN) {
        start[node] = b * CAP + lstart[t];
        cnt[node] = v;
        dis[node] = rsqrtf((float)(v + 1));
    }
    __syncthreads();

    #pragma unroll
    for (int k = 0; k < CAP / 256; ++k) {
        int i = k * 256 + t;
        if (i < fill) {
            int lc = er[k] & 255;
            int lpos = atomicAdd(&cur[lc], 1);
            rows[b * CAP + lstart[lc] + lpos] = er[k] >> 8;
        }
    }
}

// ---------------- fused prep: x->f16 | zero counters/stats | pack W1 ----------------
// wp flat idx i = ((kt*8 + nt)*64 + l)*8 + j  ->  W[kt*32 + (l>>4)*8 + j][nt*16 + (l&15)]

__global__ __launch_bounds__(256) void k_prep(const float* __restrict__ x,
                                              _Float16* __restrict__ xh,
                                              int* __restrict__ bcur,
                                              float* __restrict__ stats,   // sums+sumsq (256)
                                              const float* __restrict__ W1,
                                              _Float16* __restrict__ wp1) {
    const int b = blockIdx.x;
    const int t = threadIdx.x;
    if (b < CVT_BLKS) {
        int i = b * 256 + t;                 // float4 index, NN*16 total
        float4 v = reinterpret_cast<const float4*>(x)[i];
        half4 o;
        o.x = (_Float16)v.x; o.y = (_Float16)v.y;
        o.z = (_Float16)v.z; o.w = (_Float16)v.w;
        reinterpret_cast<half4*>(xh)[i] = o;
    } else if (b < CVT_BLKS + ZERO_BLKS) {
        int i = (b - CVT_BLKS) * 256 + t;
        if (i < 8192) bcur[i] = 0;
        else if (i < 8448) stats[i - 8192] = 0.f;
    } else {
        int i = (b - CVT_BLKS - ZERO_BLKS) * 256 + t;   // < 8192
        int j = i & 7, l = (i >> 3) & 63, nt = (i >> 9) & 7, kt = i >> 12;
        int k = kt * 32 + ((l >> 4) << 3) + j;
        int n = nt * 16 + (l & 15);
        wp1[i] = (_Float16)W1[k * 128 + n];
    }
}

// ---------------- fused layer-2 prep: BN finalize (redundant) + pack scaled W2 + sv ----------------

__global__ __launch_bounds__(256) void k_l2prep(const float* __restrict__ sums,
                                                const float* __restrict__ sumsq,
                                                const float* __restrict__ gamma,
                                                const float* __restrict__ beta,
                                                const float* __restrict__ W2,
                                                _Float16* __restrict__ wp2,
                                                float* __restrict__ sv) {
    __shared__ float scl[128];
    __shared__ float shf[128];
    const int b = blockIdx.x;
    const int t = threadIdx.x;
    if (t < 128) {
        const float n = (float)NN;
        float mean = sums[t] / n;
        float var = sumsq[t] / n - mean * mean;
        float sc = gamma[t] * rsqrtf(var + BN_EPS);
        scl[t] = sc;
        shf[t] = beta[t] - mean * sc;
    }
    __syncthreads();
    if (b < 64) {
        int i = b * 256 + t;                 // < 16384
        int j = i & 7, l = (i >> 3) & 63, nt = (i >> 9) & 7, kt = i >> 12;
        int k = kt * 32 + ((l >> 4) << 3) + j;
        int n = nt * 16 + (l & 15);
        wp2[i] = (_Float16)(W2[k * 128 + n] * scl[k]);
    } else if (t < 128) {
        float s = 0.f;
        for (int k = 0; k < 128; ++k) s += shf[k] * W2[k * 128 + t];
        sv[t] = s;
    }
}

// ---------------- pull aggregation: wave-per-node, edge-split lane groups ----------------
// L = F/4 lanes per feature slice (half4); G = 64/L groups process strided edges,
// combined with shfl_xor. Low VGPR (half4 x 4-deep) + G*4 rows in flight per wave.

__device__ __forceinline__ void fma_h4(float4& a, half4 v, float c) {
    a.x = fmaf((float)v.x, c, a.x);
    a.y = fmaf((float)v.y, c, a.y);
    a.z = fmaf((float)v.z, c, a.z);
    a.w = fmaf((float)v.w, c, a.w);
}

template<int F, bool SUMC>
__global__ __launch_bounds__(256) void k_agg(const _Float16* __restrict__ xh,
                                             const int* __restrict__ rows,
                                             const int* __restrict__ start,
                                             const int* __restrict__ cnt,
                                             const float* __restrict__ dis,
                                             _Float16* __restrict__ agg,
                                             float* __restrict__ sumcoef) {
    constexpr int L = F / 4;                 // lanes per feature slice
    constexpr int G = 64 / L;                // edge-split groups per wave
    constexpr int LOG2L = (L == 32) ? 5 : 4;
    const int t = threadIdx.x;
    const int wv = t >> 6;
    const int ln = t & 63;
    const int fid = ln & (L - 1);
    const int g = ln >> LOG2L;
    const int n = blockIdx.x * 4 + wv;       // grid = NN/4 exactly
    const int s = start[n];
    const int c = cnt[n];
    const float dn = dis[n];
    const half4* X4 = reinterpret_cast<const half4*>(xh);
    const float dn2 = dn * dn;
    float4 acc = make_float4(0.f, 0.f, 0.f, 0.f);
    if (g == 0) {                            // self term once per fid
        half4 hv = X4[n * L + fid];
        acc.x = dn2 * (float)hv.x; acc.y = dn2 * (float)hv.y;
        acc.z = dn2 * (float)hv.z; acc.w = dn2 * (float)hv.w;
    }
    float sd = 0.f;
    const int* rp = rows + s;
    int k = g;
    for (; k + 3 * G < c; k += 4 * G) {
        int r0 = rp[k], r1 = rp[k + G], r2 = rp[k + 2 * G], r3 = rp[k + 3 * G];
        float d0 = dis[r0], d1 = dis[r1], d2 = dis[r2], d3 = dis[r3];
        half4 v0 = X4[r0 * L + fid];
        half4 v1 = X4[r1 * L + fid];
        half4 v2 = X4[r2 * L + fid];
        half4 v3 = X4[r3 * L + fid];
        fma_h4(acc, v0, d0 * dn);
        fma_h4(acc, v1, d1 * dn);
        fma_h4(acc, v2, d2 * dn);
        fma_h4(acc, v3, d3 * dn);
        sd += (d0 + d1) + (d2 + d3);
    }
    for (; k < c; k += G) {
        int r = rp[k];
        float dr = dis[r];
        half4 v = X4[r * L + fid];
        fma_h4(acc, v, dr * dn);
        sd += dr;
    }
    // combine groups (offsets >= L never mix fids)
    #pragma unroll
    for (int off = L; off < 64; off <<= 1) {
        acc.x += __shfl_xor(acc.x, off);
        acc.y += __shfl_xor(acc.y, off);
        acc.z += __shfl_xor(acc.z, off);
        acc.w += __shfl_xor(acc.w, off);
        if (SUMC) sd += __shfl_xor(sd, off);
    }
    if (ln < L) {
        half4 o;
        o.x = (_Float16)acc.x; o.y = (_Float16)acc.y;
        o.z = (_Float16)acc.z; o.w = (_Float16)acc.w;
        reinterpret_cast<half4*>(agg)[n * L + fid] = o;
    }
    if (SUMC && ln == 0) sumcoef[n] = dn * sd + dn2;
}

// ---------------- MFMA GEMM: [NN,K] f16 @ packed W -> 128 cols ----------------

template<int K, bool L2E>
__global__ __launch_bounds__(256) void k_mgemm(const _Float16* __restrict__ A,
                                               const _Float16* __restrict__ Wp,
                                               const float* __restrict__ bias,
                                               const float* __restrict__ sv,
                                               const float* __restrict__ sumcoef,
                                               _Float16* __restrict__ out16,
                                               float* __restrict__ out32,
                                               float* __restrict__ sums,
                                               float* __restrict__ sumsq) {
    const int t = threadIdx.x;
    const int wv = t >> 6;
    const int ln = t & 63;
    const int cgrp = ln >> 4;
    const int ncol = ln & 15;
    const int r0 = blockIdx.x * 64 + wv * 16;
    const int arow = min(r0 + ncol, NN - 1);

    f32x4 acc[8];
    #pragma unroll
    for (int nt = 0; nt < 8; ++nt) acc[nt] = {0.f, 0.f, 0.f, 0.f};

    const half8* Ap = reinterpret_cast<const half8*>(A + arow * K + cgrp * 8);
    const half8* Bp = reinterpret_cast<const half8*>(Wp);

    #pragma unroll
    for (int kt = 0; kt < K / 32; ++kt) {
        half8 a = Ap[kt * 4];
        #pragma unroll
        for (int nt = 0; nt < 8; ++nt) {
            half8 b = Bp[(kt * 8 + nt) * 64 + ln];
            acc[nt] = __builtin_amdgcn_mfma_f32_16x16x32_f16(a, b, acc[nt], 0, 0, 0);
        }
    }

    if constexpr (!L2E) {
        __shared__ float ls[4][128];
        __shared__ float ls2[4][128];
        #pragma unroll
        for (int nt = 0; nt < 8; ++nt) {
            const int n = nt * 16 + ncol;
            const float bn = bias[n];
            float s = 0.f, s2 = 0.f;
            #pragma unroll
            for (int j = 0; j < 4; ++j) {
                int gr = r0 + cgrp * 4 + j;
                float v = acc[nt][j] + bn;
                if (gr < NN) {
                    out16[gr * 128 + n] = (_Float16)v;
                    s += v;
                    s2 += v * v;
                }
            }
            s  += __shfl_xor(s, 16);  s  += __shfl_xor(s, 32);
            s2 += __shfl_xor(s2, 16); s2 += __shfl_xor(s2, 32);
            if (ln < 16) { ls[wv][n] = s; ls2[wv][n] = s2; }
        }
        __syncthreads();
        if (t < 128) {
            atomicAdd(&sums[t], ls[0][t] + ls[1][t] + ls[2][t] + ls[3][t]);
        } else {
            int u = t - 128;
            atomicAdd(&sumsq[u], ls2[0][u] + ls2[1][u] + ls2[2][u] + ls2[3][u]);
        }
    } else {
        float scj[4];
        #pragma unroll
        for (int j = 0; j < 4; ++j) scj[j] = sumcoef[min(r0 + cgrp * 4 + j, NN - 1)];
        #pragma unroll
        for (int nt = 0; nt < 8; ++nt) {
            const int n = nt * 16 + ncol;
            const float svn = sv[n];
            const float bn = bias[n];
            #pragma unroll
            for (int j = 0; j < 4; ++j) {
                int gr = r0 + cgrp * 4 + j;
                if (gr < NN) out32[gr * 128 + n] = acc[nt][j] + scj[j] * svn + bn;
            }
        }
    }
}

// ---------------- launch ----------------

extern "C" void kernel_launch(void* const* d_in, const int* in_sizes, int n_in,
                              void* d_out, int out_size, void* d_ws, size_t ws_size,
                              hipStream_t stream) {
    const float* x     = (const float*)d_in[0];   // [NN, 64]
    const int*   ei    = (const int*)d_in[1];     // [2, E]
    const float* W1    = (const float*)d_in[2];
    const float* b1    = (const float*)d_in[3];
    const float* gamma = (const float*)d_in[4];
    const float* beta  = (const float*)d_in[5];
    const float* W2    = (const float*)d_in[6];
    const float* b2    = (const float*)d_in[7];
    float* out = (float*)d_out;                   // [NN, 128]

    const int E = in_sizes[1] / 2;
    const int* row = ei;
    const int* col = ei + E;

    // workspace layout (4-byte units)
    int*   bcur    = (int*)d_ws;                      // 8192
    int*   cnt     = bcur + 8192;                     // 102400
    int*   start   = cnt + 102400;                    // 102400
    float* dis     = (float*)(start + 102400);        // 102400
    float* sums    = dis + 102400;                    // 128
    float* sumsq   = sums + 128;                      // 128 (contiguous with sums)
    float* sv      = sumsq + 128;                     // 128 (region padded to 1024)
    float* sumcoef = sums + 1024;                     // 102400
    _Float16* wp1  = (_Float16*)(sumcoef + 102400);   // 8192 halves
    _Float16* wp2  = wp1 + 8192;                      // 16384 halves
    int*   rows    = (int*)(wp2 + 16384);             // NB*CAP
    int*   Rbase   = rows + NB * CAP;                 // reuse region
    _Float16* xh   = (_Float16*)Rbase;                //   pass A: NN*64 f16
    int*   ebuf    = Rbase + 3276800;                 //   pass A: NB*CAP ints
    _Float16* aggB = (_Float16*)Rbase;                //   pass B: NN*128 f16
    _Float16* h1   = (_Float16*)(Rbase + 6400000);    // NN*128 f16
    _Float16* aggA = (_Float16*)d_out;                // NN*64 f16 parked in d_out

    // 1. prep (cvt + zero + pack W1), CSR build
    k_prep<<<CVT_BLKS + ZERO_BLKS + PACK1_BLKS, 256, 0, stream>>>(x, xh, bcur,
                                                                  sums, W1, wp1);
    k_bin<<<(E + TILE - 1) / TILE, 256, 0, stream>>>(row, col, bcur, ebuf, E);
    k_csr<<<NB, 256, 0, stream>>>(bcur, ebuf, rows, start, cnt, dis);

    // 2. layer 1: aggregate xh (64) -> aggA f16, MFMA GEMM -> h1 f16 (+ fused BN stats)
    k_agg<64, false><<<NN / 4, 256, 0, stream>>>(xh, rows, start, cnt, dis,
                                                 aggA, nullptr);
    k_mgemm<64, false><<<(NN + 63) / 64, 256, 0, stream>>>(aggA, wp1, b1, nullptr,
                                                           nullptr, h1, nullptr,
                                                           sums, sumsq);

    // 3. fused BN finalize + W2 pack (scaled) + sv
    k_l2prep<<<65, 256, 0, stream>>>(sums, sumsq, gamma, beta, W2, wp2, sv);

    // 4. layer 2: aggregate h1 (128) -> aggB f16 + sumcoef, MFMA GEMM -> d_out f32
    k_agg<128, true><<<NN / 4, 256, 0, stream>>>(h1, rows, start, cnt, dis,
                                                 aggB, sumcoef);
    k_mgemm<128, true><<<(NN + 63) / 64, 256, 0, stream>>>(aggB, wp2, b2, sv,
                                                           sumcoef, nullptr, out,
                                                           nullptr, nullptr);
}

// Round 8
// 188.627 us; speedup vs baseline: 1.2979x; 1.2979x over previous
//
#include <hip/hip_runtime.h>

#define NN 100000
#define BN_EPS 1e-5f
#define NB 391          // buckets = ceil(NN/256), bucket b owns cols [b*256, b*256+256)
#define CAP 5120        // per-bucket edge capacity
#define TILE 4096       // edges per k_bin block

#define CVT_BLKS 6250   // NN*16 float4s / 256
#define ZERO_BLKS 33    // 8192 bcur + 256 stats = 8448 ints
#define PACK1_BLKS 32   // 64*128 / 256

typedef __attribute__((ext_vector_type(4))) _Float16 half4;
typedef __attribute__((ext_vector_type(8))) _Float16 half8;
typedef __attribute__((ext_vector_type(4))) float f32x4;

// ---------------- pass 1: bin edges by col>>8, bucket-sorted coalesced writes ----------------

__global__ __launch_bounds__(256) void k_bin(const int* __restrict__ row,
                                             const int* __restrict__ col,
                                             int* __restrict__ bcur,   // NB counters, stride 16
                                             int* __restrict__ ebuf,   // NB*CAP packed edges
                                             int E) {
    __shared__ int hist[512];
    __shared__ int excl[512];
    __shared__ int cur[512];
    __shared__ int gbase[512];
    __shared__ int sc[256];
    __shared__ int staged[TILE];
    __shared__ unsigned short bkt[TILE];
    const int t = threadIdx.x;
    const int base = blockIdx.x * TILE;
    const int nE = min(TILE, E - base);

    hist[t] = 0; hist[t + 256] = 0;
    cur[t] = 0;  cur[t + 256] = 0;
    __syncthreads();

    int er[16], ec[16];
    #pragma unroll
    for (int k = 0; k < 16; ++k) {
        int idx = base + k * 256 + t;
        if (idx < E) {
            er[k] = row[idx];
            ec[k] = col[idx];
            atomicAdd(&hist[ec[k] >> 8], 1);
        } else {
            ec[k] = -1;
        }
    }
    __syncthreads();

    int p = hist[2 * t] + hist[2 * t + 1];
    sc[t] = p;
    __syncthreads();
    for (int off = 1; off < 256; off <<= 1) {
        int add = (t >= off) ? sc[t - off] : 0;
        __syncthreads();
        sc[t] += add;
        __syncthreads();
    }
    int P = sc[t];
    excl[2 * t]     = P - p;
    excl[2 * t + 1] = P - p + hist[2 * t];
    __syncthreads();

    for (int b = t; b < NB; b += 256) {
        int h = hist[b];
        gbase[b] = h ? atomicAdd(&bcur[b * 16], h) : 0;
    }

    #pragma unroll
    for (int k = 0; k < 16; ++k) {
        int c = ec[k];
        if (c < 0) continue;
        int b = c >> 8;
        int slot = excl[b] + atomicAdd(&cur[b], 1);
        staged[slot] = (er[k] << 8) | (c & 255);
        bkt[slot] = (unsigned short)b;
    }
    __syncthreads();

    for (int i = t; i < nE; i += 256) {
        int b = bkt[i];
        int off = gbase[b] + (i - excl[b]);
        if (off < CAP) ebuf[b * CAP + off] = staged[i];
    }
}

// ---------------- pass 2: per-bucket CSR finalize ----------------

__global__ __launch_bounds__(256) void k_csr(const int* __restrict__ bcur,
                                             const int* __restrict__ ebuf,
                                             int* __restrict__ rows,
                                             int* __restrict__ start,
                                             int* __restrict__ cnt,
                                             float* __restrict__ dis) {
    __shared__ int hist[256];
    __shared__ int lstart[256];
    __shared__ int cur[256];
    __shared__ int sc[256];
    const int b = blockIdx.x;
    const int t = threadIdx.x;
    const int fill = min(bcur[b * 16], CAP);

    hist[t] = 0; cur[t] = 0;
    __syncthreads();

    int er[CAP / 256];
    #pragma unroll
    for (int k = 0; k < CAP / 256; ++k) {
        int i = k * 256 + t;
        if (i < fill) {
            er[k] = ebuf[b * CAP + i];
            atomicAdd(&hist[er[k] & 255], 1);
        }
    }
    __syncthreads();

    int v = hist[t];
    sc[t] = v;
    __syncthreads();
    for (int off = 1; off < 256; off <<= 1) {
        int add = (t >= off) ? sc[t - off] : 0;
        __syncthreads();
        sc[t] += add;
        __syncthreads();
    }
    lstart[t] = sc[t] - v;

    const int node = b * 256 + t;
    if (node < NN) {
        start[node] = b * CAP + lstart[t];
        cnt[node] = v;
        dis[node] = rsqrtf((float)(v + 1));
    }
    __syncthreads();

    #pragma unroll
    for (int k = 0; k < CAP / 256; ++k) {
        int i = k * 256 + t;
        if (i < fill) {
            int lc = er[k] & 255;
            int lpos = atomicAdd(&cur[lc], 1);
            rows[b * CAP + lstart[lc] + lpos] = er[k] >> 8;
        }
    }
}

// ---------------- fused prep: x->f16 | zero counters/stats | pack W1 ----------------
// wp flat idx i = ((kt*8 + nt)*64 + l)*8 + j  ->  W[kt*32 + (l>>4)*8 + j][nt*16 + (l&15)]

__global__ __launch_bounds__(256) void k_prep(const float* __restrict__ x,
                                              _Float16* __restrict__ xh,
                                              int* __restrict__ bcur,
                                              float* __restrict__ stats,   // sums+sumsq (256)
                                              const float* __restrict__ W1,
                                              _Float16* __restrict__ wp1) {
    const int b = blockIdx.x;
    const int t = threadIdx.x;
    if (b < CVT_BLKS) {
        int i = b * 256 + t;                 // float4 index, NN*16 total
        float4 v = reinterpret_cast<const float4*>(x)[i];
        half4 o;
        o.x = (_Float16)v.x; o.y = (_Float16)v.y;
        o.z = (_Float16)v.z; o.w = (_Float16)v.w;
        reinterpret_cast<half4*>(xh)[i] = o;
    } else if (b < CVT_BLKS + ZERO_BLKS) {
        int i = (b - CVT_BLKS) * 256 + t;
        if (i < 8192) bcur[i] = 0;
        else if (i < 8448) stats[i - 8192] = 0.f;
    } else {
        int i = (b - CVT_BLKS - ZERO_BLKS) * 256 + t;   // < 8192
        int j = i & 7, l = (i >> 3) & 63, nt = (i >> 9) & 7, kt = i >> 12;
        int k = kt * 32 + ((l >> 4) << 3) + j;
        int n = nt * 16 + (l & 15);
        wp1[i] = (_Float16)W1[k * 128 + n];
    }
}

// ---------------- layer-2 prep: BN finalize + W12 = W1 diag(s) W2 (packed) + sv ----------------
// sv[j] = sum_k (b1[k]*s[k] + beta[k] - mean[k]*s[k]) * W2[k][j]

__global__ __launch_bounds__(256) void k_l2prep(const float* __restrict__ sums,
                                                const float* __restrict__ sumsq,
                                                const float* __restrict__ gamma,
                                                const float* __restrict__ beta,
                                                const float* __restrict__ b1,
                                                const float* __restrict__ W1,
                                                const float* __restrict__ W2,
                                                _Float16* __restrict__ wp12,
                                                float* __restrict__ sv) {
    __shared__ float s_[128];
    __shared__ float f2_[128];
    const int b = blockIdx.x;
    const int t = threadIdx.x;
    if (t < 128) {
        const float n = (float)NN;
        float mean = sums[t] / n;
        float var = sumsq[t] / n - mean * mean;
        float sc = gamma[t] * rsqrtf(var + BN_EPS);
        s_[t] = sc;
        f2_[t] = b1[t] * sc + (beta[t] - mean * sc);
    }
    __syncthreads();
    if (b < 32) {
        int i = b * 256 + t;                 // 8192 packed W12 entries (K=64)
        int j = i & 7, l = (i >> 3) & 63, nt = (i >> 9) & 7, kt = i >> 12;
        int kk = kt * 32 + ((l >> 4) << 3) + j;     // 0..63
        int nn = nt * 16 + (l & 15);                 // 0..127
        float acc = 0.f;
        #pragma unroll 8
        for (int m = 0; m < 128; ++m)
            acc = fmaf(W1[kk * 128 + m] * s_[m], W2[m * 128 + nn], acc);
        wp12[i] = (_Float16)acc;
    } else if (t < 128) {
        float acc = 0.f;
        for (int k = 0; k < 128; ++k) acc = fmaf(f2_[k], W2[k * 128 + t], acc);
        sv[t] = acc;
    }
}

// ---------------- pull aggregation (f16 gather -> f32 accumulate -> f16 out) ----------------
// F=64: L=16 lanes/node, 16 nodes per 256-thr block (round-5 proven config).

__device__ __forceinline__ void fma_h4(float4& a, half4 v, float c) {
    a.x = fmaf((float)v.x, c, a.x);
    a.y = fmaf((float)v.y, c, a.y);
    a.z = fmaf((float)v.z, c, a.z);
    a.w = fmaf((float)v.w, c, a.w);
}

template<int F, bool SUMC>
__global__ __launch_bounds__(256) void k_agg(const _Float16* __restrict__ xh,
                                             const int* __restrict__ rows,
                                             const int* __restrict__ start,
                                             const int* __restrict__ cnt,
                                             const float* __restrict__ dis,
                                             _Float16* __restrict__ agg,
                                             float* __restrict__ sumcoef) {
    constexpr int L = F / 4;
    const int t = threadIdx.x;
    const int g = t / L;
    const int fid = t % L;
    const int n = blockIdx.x * (256 / L) + g;
    if (n >= NN) return;
    const int s = start[n];
    const int c = cnt[n];
    const float dn = dis[n];
    const half4* X4 = reinterpret_cast<const half4*>(xh);
    half4 hv = X4[n * L + fid];
    const float dn2 = dn * dn;
    float4 acc = make_float4(dn2 * (float)hv.x, dn2 * (float)hv.y,
                             dn2 * (float)hv.z, dn2 * (float)hv.w);
    float sd = 0.f;
    const int* rp = rows + s;
    int k = 0;
    for (; k + 4 <= c; k += 4) {
        int r0 = rp[k], r1 = rp[k + 1], r2 = rp[k + 2], r3 = rp[k + 3];
        float d0 = dis[r0], d1 = dis[r1], d2 = dis[r2], d3 = dis[r3];
        half4 v0 = X4[r0 * L + fid];
        half4 v1 = X4[r1 * L + fid];
        half4 v2 = X4[r2 * L + fid];
        half4 v3 = X4[r3 * L + fid];
        fma_h4(acc, v0, d0 * dn);
        fma_h4(acc, v1, d1 * dn);
        fma_h4(acc, v2, d2 * dn);
        fma_h4(acc, v3, d3 * dn);
        sd += (d0 + d1) + (d2 + d3);
    }
    for (; k < c; ++k) {
        int r = rp[k];
        float dr = dis[r];
        half4 v = X4[r * L + fid];
        fma_h4(acc, v, dr * dn);
        sd += dr;
    }
    half4 o;
    o.x = (_Float16)acc.x; o.y = (_Float16)acc.y;
    o.z = (_Float16)acc.z; o.w = (_Float16)acc.w;
    reinterpret_cast<half4*>(agg)[n * L + fid] = o;
    if (SUMC && fid == 0) sumcoef[n] = dn * sd + dn2;
}

// ---------------- MFMA GEMM (K=64): [NN,64] f16 @ packed W -> 128 cols ----------------
// FINAL=false: stats-only pass (h1 = y@W1 + b1, accumulate BN sums; nothing stored).
// FINAL=true:  out32 = acc + sumcoef[row]*sv[n] + bias[n] (final output).

template<bool FINAL>
__global__ __launch_bounds__(256) void k_mgemm(const _Float16* __restrict__ A,
                                               const _Float16* __restrict__ Wp,
                                               const float* __restrict__ bias,
                                               const float* __restrict__ sv,
                                               const float* __restrict__ sumcoef,
                                               float* __restrict__ out32,
                                               float* __restrict__ sums,
                                               float* __restrict__ sumsq) {
    const int t = threadIdx.x;
    const int wv = t >> 6;
    const int ln = t & 63;
    const int cgrp = ln >> 4;
    const int ncol = ln & 15;
    const int r0 = blockIdx.x * 64 + wv * 16;
    const int arow = min(r0 + ncol, NN - 1);

    f32x4 acc[8];
    #pragma unroll
    for (int nt = 0; nt < 8; ++nt) acc[nt] = {0.f, 0.f, 0.f, 0.f};

    const half8* Ap = reinterpret_cast<const half8*>(A + arow * 64 + cgrp * 8);
    const half8* Bp = reinterpret_cast<const half8*>(Wp);

    #pragma unroll
    for (int kt = 0; kt < 2; ++kt) {
        half8 a = Ap[kt * 4];
        #pragma unroll
        for (int nt = 0; nt < 8; ++nt) {
            half8 b = Bp[(kt * 8 + nt) * 64 + ln];
            acc[nt] = __builtin_amdgcn_mfma_f32_16x16x32_f16(a, b, acc[nt], 0, 0, 0);
        }
    }

    if constexpr (!FINAL) {
        __shared__ float ls[4][128];
        __shared__ float ls2[4][128];
        #pragma unroll
        for (int nt = 0; nt < 8; ++nt) {
            const int n = nt * 16 + ncol;
            const float bn = bias[n];
            float s = 0.f, s2 = 0.f;
            #pragma unroll
            for (int j = 0; j < 4; ++j) {
                int gr = r0 + cgrp * 4 + j;
                float v = acc[nt][j] + bn;
                if (gr < NN) {
                    s += v;
                    s2 += v * v;
                }
            }
            s  += __shfl_xor(s, 16);  s  += __shfl_xor(s, 32);
            s2 += __shfl_xor(s2, 16); s2 += __shfl_xor(s2, 32);
            if (ln < 16) { ls[wv][n] = s; ls2[wv][n] = s2; }
        }
        __syncthreads();
        if (t < 128) {
            atomicAdd(&sums[t], ls[0][t] + ls[1][t] + ls[2][t] + ls[3][t]);
        } else {
            int u = t - 128;
            atomicAdd(&sumsq[u], ls2[0][u] + ls2[1][u] + ls2[2][u] + ls2[3][u]);
        }
    } else {
        float scj[4];
        #pragma unroll
        for (int j = 0; j < 4; ++j) scj[j] = sumcoef[min(r0 + cgrp * 4 + j, NN - 1)];
        #pragma unroll
        for (int nt = 0; nt < 8; ++nt) {
            const int n = nt * 16 + ncol;
            const float svn = sv[n];
            const float bn = bias[n];
            #pragma unroll
            for (int j = 0; j < 4; ++j) {
                int gr = r0 + cgrp * 4 + j;
                if (gr < NN) out32[gr * 128 + n] = acc[nt][j] + scj[j] * svn + bn;
            }
        }
    }
}

// ---------------- launch ----------------

extern "C" void kernel_launch(void* const* d_in, const int* in_sizes, int n_in,
                              void* d_out, int out_size, void* d_ws, size_t ws_size,
                              hipStream_t stream) {
    const float* x     = (const float*)d_in[0];   // [NN, 64]
    const int*   ei    = (const int*)d_in[1];     // [2, E]
    const float* W1    = (const float*)d_in[2];
    const float* b1    = (const float*)d_in[3];
    const float* gamma = (const float*)d_in[4];
    const float* beta  = (const float*)d_in[5];
    const float* W2    = (const float*)d_in[6];
    const float* b2    = (const float*)d_in[7];
    float* out = (float*)d_out;                   // [NN, 128]

    const int E = in_sizes[1] / 2;
    const int* row = ei;
    const int* col = ei + E;

    // workspace layout (4-byte units)
    int*   bcur    = (int*)d_ws;                      // 8192
    int*   cnt     = bcur + 8192;                     // 102400
    int*   start   = cnt + 102400;                    // 102400
    float* dis     = (float*)(start + 102400);        // 102400
    float* sums    = dis + 102400;                    // 128
    float* sumsq   = sums + 128;                      // 128 (contiguous with sums)
    float* sv      = sumsq + 128;                     // 128 (aux region padded to 1024)
    float* sumcoef = sums + 1024;                     // 102400
    _Float16* wp1  = (_Float16*)(sumcoef + 102400);   // 8192 halves (4096 ints)
    _Float16* wp12 = wp1 + 8192;                      // 8192 halves (4096 ints)
    int*   rows    = (int*)(wp12 + 8192);             // NB*CAP
    int*   Rbase   = rows + NB * CAP;
    _Float16* xh   = (_Float16*)Rbase;                // NN*64 f16 (3,276,800 ints region)
    int*   ebuf    = Rbase + 3276800;                 // NB*CAP ints
    _Float16* y    = (_Float16*)(ebuf + NB * CAP);    // NN*64 f16
    _Float16* z    = xh;                              // overlay: xh dead after first agg

    // 1. prep (cvt + zero + pack W1), CSR build
    k_prep<<<CVT_BLKS + ZERO_BLKS + PACK1_BLKS, 256, 0, stream>>>(x, xh, bcur,
                                                                  sums, W1, wp1);
    k_bin<<<(E + TILE - 1) / TILE, 256, 0, stream>>>(row, col, bcur, ebuf, E);
    k_csr<<<NB, 256, 0, stream>>>(bcur, ebuf, rows, start, cnt, dis);

    // 2. y = agg(xh) (+ sumcoef); BN stats from y@W1+b1 (nothing materialized)
    k_agg<64, true><<<NN / 16, 256, 0, stream>>>(xh, rows, start, cnt, dis,
                                                 y, sumcoef);
    k_mgemm<false><<<(NN + 63) / 64, 256, 0, stream>>>(y, wp1, b1, nullptr,
                                                       nullptr, nullptr,
                                                       sums, sumsq);

    // 3. BN finalize + composite W12 = W1 diag(s) W2 (packed f16) + sv
    k_l2prep<<<33, 256, 0, stream>>>(sums, sumsq, gamma, beta, b1, W1, W2,
                                     wp12, sv);

    // 4. z = agg(y); out = z @ W12 + sumcoef*sv + b2
    k_agg<64, false><<<NN / 16, 256, 0, stream>>>(y, rows, start, cnt, dis,
                                                  z, nullptr);
    k_mgemm<true><<<(NN + 63) / 64, 256, 0, stream>>>(z, wp12, b2, sv,
                                                      sumcoef, out,
                                                      nullptr, nullptr);
}

// Round 9
// 155.599 us; speedup vs baseline: 1.5733x; 1.2123x over previous
//
#include <hip/hip_runtime.h>

#define NN 100000
#define BN_EPS 1e-5f
#define NB 391          // buckets = ceil(NN/256), bucket b owns cols [b*256, b*256+256)
#define CAP 5120        // per-bucket edge capacity
#define TILE 4096       // edges per k_bin block

#define NREP 16         // BN-stats replicas (atomic-contention spreading)
#define CVT_BLKS 6250   // NN*16 float4s / 256
#define ZERO_BLKS 48    // 8192 bcur + NREP*256 stats = 12288 ints
#define PACK1_BLKS 32   // 64*128 / 256

typedef __attribute__((ext_vector_type(4))) _Float16 half4;
typedef __attribute__((ext_vector_type(8))) _Float16 half8;
typedef __attribute__((ext_vector_type(4))) float f32x4;

// ---------------- pass 1: bin edges by col>>8, bucket-sorted coalesced writes ----------------

__global__ __launch_bounds__(256) void k_bin(const int* __restrict__ row,
                                             const int* __restrict__ col,
                                             int* __restrict__ bcur,   // NB counters, stride 16
                                             int* __restrict__ ebuf,   // NB*CAP packed edges
                                             int E) {
    __shared__ int hist[512];
    __shared__ int excl[512];
    __shared__ int cur[512];
    __shared__ int gbase[512];
    __shared__ int sc[256];
    __shared__ int staged[TILE];
    __shared__ unsigned short bkt[TILE];
    const int t = threadIdx.x;
    const int base = blockIdx.x * TILE;
    const int nE = min(TILE, E - base);

    hist[t] = 0; hist[t + 256] = 0;
    cur[t] = 0;  cur[t + 256] = 0;
    __syncthreads();

    int er[16], ec[16];
    #pragma unroll
    for (int k = 0; k < 16; ++k) {
        int idx = base + k * 256 + t;
        if (idx < E) {
            er[k] = row[idx];
            ec[k] = col[idx];
            atomicAdd(&hist[ec[k] >> 8], 1);
        } else {
            ec[k] = -1;
        }
    }
    __syncthreads();

    int p = hist[2 * t] + hist[2 * t + 1];
    sc[t] = p;
    __syncthreads();
    for (int off = 1; off < 256; off <<= 1) {
        int add = (t >= off) ? sc[t - off] : 0;
        __syncthreads();
        sc[t] += add;
        __syncthreads();
    }
    int P = sc[t];
    excl[2 * t]     = P - p;
    excl[2 * t + 1] = P - p + hist[2 * t];
    __syncthreads();

    for (int b = t; b < NB; b += 256) {
        int h = hist[b];
        gbase[b] = h ? atomicAdd(&bcur[b * 16], h) : 0;
    }

    #pragma unroll
    for (int k = 0; k < 16; ++k) {
        int c = ec[k];
        if (c < 0) continue;
        int b = c >> 8;
        int slot = excl[b] + atomicAdd(&cur[b], 1);
        staged[slot] = (er[k] << 8) | (c & 255);
        bkt[slot] = (unsigned short)b;
    }
    __syncthreads();

    for (int i = t; i < nE; i += 256) {
        int b = bkt[i];
        int off = gbase[b] + (i - excl[b]);
        if (off < CAP) ebuf[b * CAP + off] = staged[i];
    }
}

// ---------------- pass 2: per-bucket CSR finalize ----------------

__global__ __launch_bounds__(256) void k_csr(const int* __restrict__ bcur,
                                             const int* __restrict__ ebuf,
                                             int* __restrict__ rows,
                                             int* __restrict__ start,
                                             int* __restrict__ cnt,
                                             float* __restrict__ dis) {
    __shared__ int hist[256];
    __shared__ int lstart[256];
    __shared__ int cur[256];
    __shared__ int sc[256];
    const int b = blockIdx.x;
    const int t = threadIdx.x;
    const int fill = min(bcur[b * 16], CAP);

    hist[t] = 0; cur[t] = 0;
    __syncthreads();

    int er[CAP / 256];
    #pragma unroll
    for (int k = 0; k < CAP / 256; ++k) {
        int i = k * 256 + t;
        if (i < fill) {
            er[k] = ebuf[b * CAP + i];
            atomicAdd(&hist[er[k] & 255], 1);
        }
    }
    __syncthreads();

    int v = hist[t];
    sc[t] = v;
    __syncthreads();
    for (int off = 1; off < 256; off <<= 1) {
        int add = (t >= off) ? sc[t - off] : 0;
        __syncthreads();
        sc[t] += add;
        __syncthreads();
    }
    lstart[t] = sc[t] - v;

    const int node = b * 256 + t;
    if (node < NN) {
        start[node] = b * CAP + lstart[t];
        cnt[node] = v;
        dis[node] = rsqrtf((float)(v + 1));
    }
    __syncthreads();

    #pragma unroll
    for (int k = 0; k < CAP / 256; ++k) {
        int i = k * 256 + t;
        if (i < fill) {
            int lc = er[k] & 255;
            int lpos = atomicAdd(&cur[lc], 1);
            rows[b * CAP + lstart[lc] + lpos] = er[k] >> 8;
        }
    }
}

// ---------------- fused prep: x->f16 | zero counters/stats | pack W1 ----------------
// wp flat idx i = ((kt*8 + nt)*64 + l)*8 + j  ->  W[kt*32 + (l>>4)*8 + j][nt*16 + (l&15)]

__global__ __launch_bounds__(256) void k_prep(const float* __restrict__ x,
                                              _Float16* __restrict__ xh,
                                              int* __restrict__ bcur,
                                              float* __restrict__ stats,   // NREP*256 floats
                                              const float* __restrict__ W1,
                                              _Float16* __restrict__ wp1) {
    const int b = blockIdx.x;
    const int t = threadIdx.x;
    if (b < CVT_BLKS) {
        int i = b * 256 + t;                 // float4 index, NN*16 total
        float4 v = reinterpret_cast<const float4*>(x)[i];
        half4 o;
        o.x = (_Float16)v.x; o.y = (_Float16)v.y;
        o.z = (_Float16)v.z; o.w = (_Float16)v.w;
        reinterpret_cast<half4*>(xh)[i] = o;
    } else if (b < CVT_BLKS + ZERO_BLKS) {
        int i = (b - CVT_BLKS) * 256 + t;
        if (i < 8192) bcur[i] = 0;
        else if (i < 8192 + NREP * 256) stats[i - 8192] = 0.f;
    } else {
        int i = (b - CVT_BLKS - ZERO_BLKS) * 256 + t;   // < 8192
        int j = i & 7, l = (i >> 3) & 63, nt = (i >> 9) & 7, kt = i >> 12;
        int k = kt * 32 + ((l >> 4) << 3) + j;
        int n = nt * 16 + (l & 15);
        wp1[i] = (_Float16)W1[k * 128 + n];
    }
}

// ---------------- layer-2 prep: rep-sum + BN finalize + W12 = W1 diag(s) W2 + sv ----------------
// sv[j] = sum_k (b1[k]*s[k] + beta[k] - mean[k]*s[k]) * W2[k][j]

__global__ __launch_bounds__(256) void k_l2prep(const float* __restrict__ stats,
                                                const float* __restrict__ gamma,
                                                const float* __restrict__ beta,
                                                const float* __restrict__ b1,
                                                const float* __restrict__ W1,
                                                const float* __restrict__ W2,
                                                _Float16* __restrict__ wp12,
                                                float* __restrict__ sv) {
    __shared__ float s_[128];
    __shared__ float f2_[128];
    const int b = blockIdx.x;
    const int t = threadIdx.x;
    if (t < 128) {
        float sum = 0.f, sum2 = 0.f;
        #pragma unroll
        for (int r = 0; r < NREP; ++r) {
            sum  += stats[r * 256 + t];
            sum2 += stats[r * 256 + 128 + t];
        }
        const float n = (float)NN;
        float mean = sum / n;
        float var = sum2 / n - mean * mean;
        float sc = gamma[t] * rsqrtf(var + BN_EPS);
        s_[t] = sc;
        f2_[t] = b1[t] * sc + (beta[t] - mean * sc);
    }
    __syncthreads();
    if (b < 32) {
        int i = b * 256 + t;                 // 8192 packed W12 entries (K=64)
        int j = i & 7, l = (i >> 3) & 63, nt = (i >> 9) & 7, kt = i >> 12;
        int kk = kt * 32 + ((l >> 4) << 3) + j;     // 0..63
        int nn = nt * 16 + (l & 15);                 // 0..127
        float acc = 0.f;
        #pragma unroll 8
        for (int m = 0; m < 128; ++m)
            acc = fmaf(W1[kk * 128 + m] * s_[m], W2[m * 128 + nn], acc);
        wp12[i] = (_Float16)acc;
    } else if (t < 128) {
        float acc = 0.f;
        for (int k = 0; k < 128; ++k) acc = fmaf(f2_[k], W2[k * 128 + t], acc);
        sv[t] = acc;
    }
}

// ---------------- pull aggregation (f16 gather -> f32 accumulate -> f16 out) ----------------
// F=64: L=16 lanes/node, 16 nodes per 256-thr block (round-5 proven config).

__device__ __forceinline__ void fma_h4(float4& a, half4 v, float c) {
    a.x = fmaf((float)v.x, c, a.x);
    a.y = fmaf((float)v.y, c, a.y);
    a.z = fmaf((float)v.z, c, a.z);
    a.w = fmaf((float)v.w, c, a.w);
}

template<int F, bool SUMC>
__global__ __launch_bounds__(256) void k_agg(const _Float16* __restrict__ xh,
                                             const int* __restrict__ rows,
                                             const int* __restrict__ start,
                                             const int* __restrict__ cnt,
                                             const float* __restrict__ dis,
                                             _Float16* __restrict__ agg,
                                             float* __restrict__ sumcoef) {
    constexpr int L = F / 4;
    const int t = threadIdx.x;
    const int g = t / L;
    const int fid = t % L;
    const int n = blockIdx.x * (256 / L) + g;
    if (n >= NN) return;
    const int s = start[n];
    const int c = cnt[n];
    const float dn = dis[n];
    const half4* X4 = reinterpret_cast<const half4*>(xh);
    half4 hv = X4[n * L + fid];
    const float dn2 = dn * dn;
    float4 acc = make_float4(dn2 * (float)hv.x, dn2 * (float)hv.y,
                             dn2 * (float)hv.z, dn2 * (float)hv.w);
    float sd = 0.f;
    const int* rp = rows + s;
    int k = 0;
    for (; k + 4 <= c; k += 4) {
        int r0 = rp[k], r1 = rp[k + 1], r2 = rp[k + 2], r3 = rp[k + 3];
        float d0 = dis[r0], d1 = dis[r1], d2 = dis[r2], d3 = dis[r3];
        half4 v0 = X4[r0 * L + fid];
        half4 v1 = X4[r1 * L + fid];
        half4 v2 = X4[r2 * L + fid];
        half4 v3 = X4[r3 * L + fid];
        fma_h4(acc, v0, d0 * dn);
        fma_h4(acc, v1, d1 * dn);
        fma_h4(acc, v2, d2 * dn);
        fma_h4(acc, v3, d3 * dn);
        sd += (d0 + d1) + (d2 + d3);
    }
    for (; k < c; ++k) {
        int r = rp[k];
        float dr = dis[r];
        half4 v = X4[r * L + fid];
        fma_h4(acc, v, dr * dn);
        sd += dr;
    }
    half4 o;
    o.x = (_Float16)acc.x; o.y = (_Float16)acc.y;
    o.z = (_Float16)acc.z; o.w = (_Float16)acc.w;
    reinterpret_cast<half4*>(agg)[n * L + fid] = o;
    if (SUMC && fid == 0) sumcoef[n] = dn * sd + dn2;
}

// ---------------- MFMA GEMM (K=64): [NN,64] f16 @ packed W -> 128 cols ----------------
// FINAL=false: stats-only pass (h1 = y@W1 + b1, accumulate BN sums into replica).
// FINAL=true:  out32 = acc + sumcoef[row]*sv[n] + bias[n] (final output).

template<bool FINAL>
__global__ __launch_bounds__(256) void k_mgemm(const _Float16* __restrict__ A,
                                               const _Float16* __restrict__ Wp,
                                               const float* __restrict__ bias,
                                               const float* __restrict__ sv,
                                               const float* __restrict__ sumcoef,
                                               float* __restrict__ out32,
                                               float* __restrict__ stats) {
    const int t = threadIdx.x;
    const int wv = t >> 6;
    const int ln = t & 63;
    const int cgrp = ln >> 4;
    const int ncol = ln & 15;
    const int r0 = blockIdx.x * 64 + wv * 16;
    const int arow = min(r0 + ncol, NN - 1);

    f32x4 acc[8];
    #pragma unroll
    for (int nt = 0; nt < 8; ++nt) acc[nt] = {0.f, 0.f, 0.f, 0.f};

    const half8* Ap = reinterpret_cast<const half8*>(A + arow * 64 + cgrp * 8);
    const half8* Bp = reinterpret_cast<const half8*>(Wp);

    #pragma unroll
    for (int kt = 0; kt < 2; ++kt) {
        half8 a = Ap[kt * 4];
        #pragma unroll
        for (int nt = 0; nt < 8; ++nt) {
            half8 b = Bp[(kt * 8 + nt) * 64 + ln];
            acc[nt] = __builtin_amdgcn_mfma_f32_16x16x32_f16(a, b, acc[nt], 0, 0, 0);
        }
    }

    if constexpr (!FINAL) {
        __shared__ float ls[4][128];
        __shared__ float ls2[4][128];
        #pragma unroll
        for (int nt = 0; nt < 8; ++nt) {
            const int n = nt * 16 + ncol;
            const float bn = bias[n];
            float s = 0.f, s2 = 0.f;
            #pragma unroll
            for (int j = 0; j < 4; ++j) {
                int gr = r0 + cgrp * 4 + j;
                float v = acc[nt][j] + bn;
                if (gr < NN) {
                    s += v;
                    s2 += v * v;
                }
            }
            s  += __shfl_xor(s, 16);  s  += __shfl_xor(s, 32);
            s2 += __shfl_xor(s2, 16); s2 += __shfl_xor(s2, 32);
            if (ln < 16) { ls[wv][n] = s; ls2[wv][n] = s2; }
        }
        __syncthreads();
        float* rep = stats + (blockIdx.x & (NREP - 1)) * 256;
        if (t < 128) {
            atomicAdd(&rep[t], ls[0][t] + ls[1][t] + ls[2][t] + ls[3][t]);
        } else {
            int u = t - 128;
            atomicAdd(&rep[128 + u], ls2[0][u] + ls2[1][u] + ls2[2][u] + ls2[3][u]);
        }
    } else {
        float scj[4];
        #pragma unroll
        for (int j = 0; j < 4; ++j) scj[j] = sumcoef[min(r0 + cgrp * 4 + j, NN - 1)];
        #pragma unroll
        for (int nt = 0; nt < 8; ++nt) {
            const int n = nt * 16 + ncol;
            const float svn = sv[n];
            const float bn = bias[n];
            #pragma unroll
            for (int j = 0; j < 4; ++j) {
                int gr = r0 + cgrp * 4 + j;
                if (gr < NN) out32[gr * 128 + n] = acc[nt][j] + scj[j] * svn + bn;
            }
        }
    }
}

// ---------------- launch ----------------

extern "C" void kernel_launch(void* const* d_in, const int* in_sizes, int n_in,
                              void* d_out, int out_size, void* d_ws, size_t ws_size,
                              hipStream_t stream) {
    const float* x     = (const float*)d_in[0];   // [NN, 64]
    const int*   ei    = (const int*)d_in[1];     // [2, E]
    const float* W1    = (const float*)d_in[2];
    const float* b1    = (const float*)d_in[3];
    const float* gamma = (const float*)d_in[4];
    const float* beta  = (const float*)d_in[5];
    const float* W2    = (const float*)d_in[6];
    const float* b2    = (const float*)d_in[7];
    float* out = (float*)d_out;                   // [NN, 128]

    const int E = in_sizes[1] / 2;
    const int* row = ei;
    const int* col = ei + E;

    // workspace layout (4-byte units)
    int*   bcur    = (int*)d_ws;                      // 8192
    int*   cnt     = bcur + 8192;                     // 102400
    int*   start   = cnt + 102400;                    // 102400
    float* dis     = (float*)(start + 102400);        // 102400
    float* stats   = dis + 102400;                    // NREP*256 = 4096
    float* sv      = stats + 4096;                    // 128 (pad to 1024)
    float* sumcoef = stats + 5120;                    // 102400
    _Float16* wp1  = (_Float16*)(sumcoef + 102400);   // 8192 halves (4096 ints)
    _Float16* wp12 = wp1 + 8192;                      // 8192 halves (4096 ints)
    int*   rows    = (int*)(wp12 + 8192);             // NB*CAP
    int*   Rbase   = rows + NB * CAP;
    _Float16* xh   = (_Float16*)Rbase;                // NN*64 f16 (3,276,800 ints region)
    int*   ebuf    = Rbase + 3276800;                 // NB*CAP ints
    _Float16* y    = (_Float16*)(ebuf + NB * CAP);    // NN*64 f16
    _Float16* z    = xh;                              // overlay: xh dead after first agg

    // 1. prep (cvt + zero + pack W1), CSR build
    k_prep<<<CVT_BLKS + ZERO_BLKS + PACK1_BLKS, 256, 0, stream>>>(x, xh, bcur,
                                                                  stats, W1, wp1);
    k_bin<<<(E + TILE - 1) / TILE, 256, 0, stream>>>(row, col, bcur, ebuf, E);
    k_csr<<<NB, 256, 0, stream>>>(bcur, ebuf, rows, start, cnt, dis);

    // 2. y = agg(xh) (+ sumcoef); BN stats from y@W1+b1 (nothing materialized)
    k_agg<64, true><<<NN / 16, 256, 0, stream>>>(xh, rows, start, cnt, dis,
                                                 y, sumcoef);
    k_mgemm<false><<<(NN + 63) / 64, 256, 0, stream>>>(y, wp1, b1, nullptr,
                                                       nullptr, nullptr, stats);

    // 3. BN finalize (rep-sum) + composite W12 = W1 diag(s) W2 (packed f16) + sv
    k_l2prep<<<33, 256, 0, stream>>>(stats, gamma, beta, b1, W1, W2, wp12, sv);

    // 4. z = agg(y); out = z @ W12 + sumcoef*sv + b2
    k_agg<64, false><<<NN / 16, 256, 0, stream>>>(y, rows, start, cnt, dis,
                                                  z, nullptr);
    k_mgemm<true><<<(NN + 63) / 64, 256, 0, stream>>>(z, wp12, b2, sv,
                                                      sumcoef, out, nullptr);
}

// Round 10
// 148.389 us; speedup vs baseline: 1.6498x; 1.0486x over previous
//
#include <hip/hip_runtime.h>

#define NN 100000
#define BN_EPS 1e-5f
#define NB 391          // buckets = ceil(NN/256), bucket b owns cols [b*256, b*256+256)
#define CAP 5120        // per-bucket edge capacity
#define TILE 4096       // edges per k_bin block

#define NREP 16         // BN-stats replicas (atomic-contention spreading)
#define CVT_BLKS 6250   // NN*16 float4s / 256
#define AGG_BLKS 6250   // NN/16
#define ZERO_BLKS 48    // 8192 bcur + NREP*256 stats = 12288 ints
#define PACK1_BLKS 32   // 64*128 / 256

typedef __attribute__((ext_vector_type(4))) _Float16 half4;
typedef __attribute__((ext_vector_type(8))) _Float16 half8;
typedef __attribute__((ext_vector_type(4))) float f32x4;

// ---------------- prep0: zero counters/stats | pack W1 ----------------
// wp flat idx i = ((kt*8 + nt)*64 + l)*8 + j  ->  W[kt*32 + (l>>4)*8 + j][nt*16 + (l&15)]

__global__ __launch_bounds__(256) void k_prep0(int* __restrict__ bcur,
                                               float* __restrict__ stats,
                                               const float* __restrict__ W1,
                                               _Float16* __restrict__ wp1) {
    const int b = blockIdx.x;
    const int t = threadIdx.x;
    if (b < ZERO_BLKS) {
        int i = b * 256 + t;
        if (i < 8192) bcur[i] = 0;
        else stats[i - 8192] = 0.f;              // NREP*256 = 4096
    } else {
        int i = (b - ZERO_BLKS) * 256 + t;       // < 8192
        int j = i & 7, l = (i >> 3) & 63, nt = (i >> 9) & 7, kt = i >> 12;
        int k = kt * 32 + ((l >> 4) << 3) + j;
        int n = nt * 16 + (l & 15);
        wp1[i] = (_Float16)W1[k * 128 + n];
    }
}

// ---------------- pass 1 (fused): bin edges by col>>8 | x->f16 convert ----------------

__global__ __launch_bounds__(256) void k_binc(const int* __restrict__ row,
                                              const int* __restrict__ col,
                                              int* __restrict__ bcur,   // NB counters, stride 16
                                              int* __restrict__ ebuf,   // NB*CAP packed edges
                                              int E, int binBlks,
                                              const float* __restrict__ x,
                                              _Float16* __restrict__ xh) {
    __shared__ int hist[512];
    __shared__ int excl[512];
    __shared__ int cur[512];
    __shared__ int gbase[512];
    __shared__ int sc[256];
    __shared__ int staged[TILE];
    __shared__ unsigned short bkt[TILE];
    const int t = threadIdx.x;

    if (blockIdx.x >= binBlks) {
        // cvt role: convert 256 float4s of x to f16
        int i = (blockIdx.x - binBlks) * 256 + t;    // < NN*16 exactly
        float4 v = reinterpret_cast<const float4*>(x)[i];
        half4 o;
        o.x = (_Float16)v.x; o.y = (_Float16)v.y;
        o.z = (_Float16)v.z; o.w = (_Float16)v.w;
        reinterpret_cast<half4*>(xh)[i] = o;
        return;
    }

    const int base = blockIdx.x * TILE;
    const int nE = min(TILE, E - base);

    hist[t] = 0; hist[t + 256] = 0;
    cur[t] = 0;  cur[t + 256] = 0;
    __syncthreads();

    int er[16], ec[16];
    #pragma unroll
    for (int k = 0; k < 16; ++k) {
        int idx = base + k * 256 + t;
        if (idx < E) {
            er[k] = row[idx];
            ec[k] = col[idx];
            atomicAdd(&hist[ec[k] >> 8], 1);
        } else {
            ec[k] = -1;
        }
    }
    __syncthreads();

    int p = hist[2 * t] + hist[2 * t + 1];
    sc[t] = p;
    __syncthreads();
    for (int off = 1; off < 256; off <<= 1) {
        int add = (t >= off) ? sc[t - off] : 0;
        __syncthreads();
        sc[t] += add;
        __syncthreads();
    }
    int P = sc[t];
    excl[2 * t]     = P - p;
    excl[2 * t + 1] = P - p + hist[2 * t];
    __syncthreads();

    for (int b = t; b < NB; b += 256) {
        int h = hist[b];
        gbase[b] = h ? atomicAdd(&bcur[b * 16], h) : 0;
    }

    #pragma unroll
    for (int k = 0; k < 16; ++k) {
        int c = ec[k];
        if (c < 0) continue;
        int b = c >> 8;
        int slot = excl[b] + atomicAdd(&cur[b], 1);
        staged[slot] = (er[k] << 8) | (c & 255);
        bkt[slot] = (unsigned short)b;
    }
    __syncthreads();

    for (int i = t; i < nE; i += 256) {
        int b = bkt[i];
        int off = gbase[b] + (i - excl[b]);
        if (off < CAP) ebuf[b * CAP + off] = staged[i];
    }
}

// ---------------- pass 2: per-bucket CSR finalize ----------------

__global__ __launch_bounds__(256) void k_csr(const int* __restrict__ bcur,
                                             const int* __restrict__ ebuf,
                                             int* __restrict__ rows,
                                             int* __restrict__ start,
                                             int* __restrict__ cnt,
                                             float* __restrict__ dis) {
    __shared__ int hist[256];
    __shared__ int lstart[256];
    __shared__ int cur[256];
    __shared__ int sc[256];
    const int b = blockIdx.x;
    const int t = threadIdx.x;
    const int fill = min(bcur[b * 16], CAP);

    hist[t] = 0; cur[t] = 0;
    __syncthreads();

    int er[CAP / 256];
    #pragma unroll
    for (int k = 0; k < CAP / 256; ++k) {
        int i = k * 256 + t;
        if (i < fill) {
            er[k] = ebuf[b * CAP + i];
            atomicAdd(&hist[er[k] & 255], 1);
        }
    }
    __syncthreads();

    int v = hist[t];
    sc[t] = v;
    __syncthreads();
    for (int off = 1; off < 256; off <<= 1) {
        int add = (t >= off) ? sc[t - off] : 0;
        __syncthreads();
        sc[t] += add;
        __syncthreads();
    }
    lstart[t] = sc[t] - v;

    const int node = b * 256 + t;
    if (node < NN) {
        start[node] = b * CAP + lstart[t];
        cnt[node] = v;
        dis[node] = rsqrtf((float)(v + 1));
    }
    __syncthreads();

    #pragma unroll
    for (int k = 0; k < CAP / 256; ++k) {
        int i = k * 256 + t;
        if (i < fill) {
            int lc = er[k] & 255;
            int lpos = atomicAdd(&cur[lc], 1);
            rows[b * CAP + lstart[lc] + lpos] = er[k] >> 8;
        }
    }
}

// ---------------- pull aggregation body (F=64: L=16 lanes/node, 16 nodes/block) ----------------

__device__ __forceinline__ void fma_h4(float4& a, half4 v, float c) {
    a.x = fmaf((float)v.x, c, a.x);
    a.y = fmaf((float)v.y, c, a.y);
    a.z = fmaf((float)v.z, c, a.z);
    a.w = fmaf((float)v.w, c, a.w);
}

template<bool SUMC>
__device__ __forceinline__ void agg_body(int blk,
                                         const _Float16* __restrict__ xh,
                                         const int* __restrict__ rows,
                                         const int* __restrict__ start,
                                         const int* __restrict__ cnt,
                                         const float* __restrict__ dis,
                                         _Float16* __restrict__ agg,
                                         float* __restrict__ sumcoef) {
    constexpr int L = 16;
    const int t = threadIdx.x;
    const int g = t / L;
    const int fid = t % L;
    const int n = blk * 16 + g;
    if (n >= NN) return;
    const int s = start[n];
    const int c = cnt[n];
    const float dn = dis[n];
    const half4* X4 = reinterpret_cast<const half4*>(xh);
    half4 hv = X4[n * L + fid];
    const float dn2 = dn * dn;
    float4 acc = make_float4(dn2 * (float)hv.x, dn2 * (float)hv.y,
                             dn2 * (float)hv.z, dn2 * (float)hv.w);
    float sd = 0.f;
    const int* rp = rows + s;
    int k = 0;
    for (; k + 4 <= c; k += 4) {
        int r0 = rp[k], r1 = rp[k + 1], r2 = rp[k + 2], r3 = rp[k + 3];
        float d0 = dis[r0], d1 = dis[r1], d2 = dis[r2], d3 = dis[r3];
        half4 v0 = X4[r0 * L + fid];
        half4 v1 = X4[r1 * L + fid];
        half4 v2 = X4[r2 * L + fid];
        half4 v3 = X4[r3 * L + fid];
        fma_h4(acc, v0, d0 * dn);
        fma_h4(acc, v1, d1 * dn);
        fma_h4(acc, v2, d2 * dn);
        fma_h4(acc, v3, d3 * dn);
        sd += (d0 + d1) + (d2 + d3);
    }
    for (; k < c; ++k) {
        int r = rp[k];
        float dr = dis[r];
        half4 v = X4[r * L + fid];
        fma_h4(acc, v, dr * dn);
        sd += dr;
    }
    half4 o;
    o.x = (_Float16)acc.x; o.y = (_Float16)acc.y;
    o.z = (_Float16)acc.z; o.w = (_Float16)acc.w;
    reinterpret_cast<half4*>(agg)[n * L + fid] = o;
    if (SUMC && fid == 0) sumcoef[n] = dn * sd + dn2;
}

// ---------------- layer-2 prep body: rep-sum + BN finalize + W12 + sv ----------------

__device__ __forceinline__ void l2prep_body(int bb,
                                            const float* __restrict__ stats,
                                            const float* __restrict__ gamma,
                                            const float* __restrict__ beta,
                                            const float* __restrict__ b1,
                                            const float* __restrict__ W1,
                                            const float* __restrict__ W2,
                                            _Float16* __restrict__ wp12,
                                            float* __restrict__ sv) {
    __shared__ float s_[128];
    __shared__ float f2_[128];
    const int t = threadIdx.x;
    if (t < 128) {
        float sum = 0.f, sum2 = 0.f;
        #pragma unroll
        for (int r = 0; r < NREP; ++r) {
            sum  += stats[r * 256 + t];
            sum2 += stats[r * 256 + 128 + t];
        }
        const float n = (float)NN;
        float mean = sum / n;
        float var = sum2 / n - mean * mean;
        float sc = gamma[t] * rsqrtf(var + BN_EPS);
        s_[t] = sc;
        f2_[t] = b1[t] * sc + (beta[t] - mean * sc);
    }
    __syncthreads();
    if (bb < 32) {
        int i = bb * 256 + t;                // 8192 packed W12 entries (K=64)
        int j = i & 7, l = (i >> 3) & 63, nt = (i >> 9) & 7, kt = i >> 12;
        int kk = kt * 32 + ((l >> 4) << 3) + j;     // 0..63
        int nn = nt * 16 + (l & 15);                 // 0..127
        float acc = 0.f;
        #pragma unroll 8
        for (int m = 0; m < 128; ++m)
            acc = fmaf(W1[kk * 128 + m] * s_[m], W2[m * 128 + nn], acc);
        wp12[i] = (_Float16)acc;
    } else if (t < 128) {
        float acc = 0.f;
        for (int k = 0; k < 128; ++k) acc = fmaf(f2_[k], W2[k * 128 + t], acc);
        sv[t] = acc;
    }
}

// ---------------- standalone agg (y pass, with sumcoef) ----------------

__global__ __launch_bounds__(256) void k_aggy(const _Float16* __restrict__ xh,
                                              const int* __restrict__ rows,
                                              const int* __restrict__ start,
                                              const int* __restrict__ cnt,
                                              const float* __restrict__ dis,
                                              _Float16* __restrict__ agg,
                                              float* __restrict__ sumcoef) {
    agg_body<true>(blockIdx.x, xh, rows, start, cnt, dis, agg, sumcoef);
}

// ---------------- fused: agg (z pass) | l2prep ----------------

__global__ __launch_bounds__(256) void k_aggz(const _Float16* __restrict__ y,
                                              const int* __restrict__ rows,
                                              const int* __restrict__ start,
                                              const int* __restrict__ cnt,
                                              const float* __restrict__ dis,
                                              _Float16* __restrict__ z,
                                              const float* __restrict__ stats,
                                              const float* __restrict__ gamma,
                                              const float* __restrict__ beta,
                                              const float* __restrict__ b1,
                                              const float* __restrict__ W1,
                                              const float* __restrict__ W2,
                                              _Float16* __restrict__ wp12,
                                              float* __restrict__ sv) {
    if (blockIdx.x < AGG_BLKS) {
        agg_body<false>(blockIdx.x, y, rows, start, cnt, dis, z, nullptr);
    } else {
        l2prep_body(blockIdx.x - AGG_BLKS, stats, gamma, beta, b1, W1, W2,
                    wp12, sv);
    }
}

// ---------------- MFMA GEMM (K=64): [NN,64] f16 @ packed W -> 128 cols ----------------
// FINAL=false: stats-only pass (h1 = y@W1 + b1, accumulate BN sums into replica).
// FINAL=true:  out32 = acc + sumcoef[row]*sv[n] + bias[n] (final output).

template<bool FINAL>
__global__ __launch_bounds__(256) void k_mgemm(const _Float16* __restrict__ A,
                                               const _Float16* __restrict__ Wp,
                                               const float* __restrict__ bias,
                                               const float* __restrict__ sv,
                                               const float* __restrict__ sumcoef,
                                               float* __restrict__ out32,
                                               float* __restrict__ stats) {
    const int t = threadIdx.x;
    const int wv = t >> 6;
    const int ln = t & 63;
    const int cgrp = ln >> 4;
    const int ncol = ln & 15;
    const int r0 = blockIdx.x * 64 + wv * 16;
    const int arow = min(r0 + ncol, NN - 1);

    f32x4 acc[8];
    #pragma unroll
    for (int nt = 0; nt < 8; ++nt) acc[nt] = {0.f, 0.f, 0.f, 0.f};

    const half8* Ap = reinterpret_cast<const half8*>(A + arow * 64 + cgrp * 8);
    const half8* Bp = reinterpret_cast<const half8*>(Wp);

    #pragma unroll
    for (int kt = 0; kt < 2; ++kt) {
        half8 a = Ap[kt * 4];
        #pragma unroll
        for (int nt = 0; nt < 8; ++nt) {
            half8 b = Bp[(kt * 8 + nt) * 64 + ln];
            acc[nt] = __builtin_amdgcn_mfma_f32_16x16x32_f16(a, b, acc[nt], 0, 0, 0);
        }
    }

    if constexpr (!FINAL) {
        __shared__ float ls[4][128];
        __shared__ float ls2[4][128];
        #pragma unroll
        for (int nt = 0; nt < 8; ++nt) {
            const int n = nt * 16 + ncol;
            const float bn = bias[n];
            float s = 0.f, s2 = 0.f;
            #pragma unroll
            for (int j = 0; j < 4; ++j) {
                int gr = r0 + cgrp * 4 + j;
                float v = acc[nt][j] + bn;
                if (gr < NN) {
                    s += v;
                    s2 += v * v;
                }
            }
            s  += __shfl_xor(s, 16);  s  += __shfl_xor(s, 32);
            s2 += __shfl_xor(s2, 16); s2 += __shfl_xor(s2, 32);
            if (ln < 16) { ls[wv][n] = s; ls2[wv][n] = s2; }
        }
        __syncthreads();
        float* rep = stats + (blockIdx.x & (NREP - 1)) * 256;
        if (t < 128) {
            atomicAdd(&rep[t], ls[0][t] + ls[1][t] + ls[2][t] + ls[3][t]);
        } else {
            int u = t - 128;
            atomicAdd(&rep[128 + u], ls2[0][u] + ls2[1][u] + ls2[2][u] + ls2[3][u]);
        }
    } else {
        float scj[4];
        #pragma unroll
        for (int j = 0; j < 4; ++j) scj[j] = sumcoef[min(r0 + cgrp * 4 + j, NN - 1)];
        #pragma unroll
        for (int nt = 0; nt < 8; ++nt) {
            const int n = nt * 16 + ncol;
            const float svn = sv[n];
            const float bn = bias[n];
            #pragma unroll
            for (int j = 0; j < 4; ++j) {
                int gr = r0 + cgrp * 4 + j;
                if (gr < NN) out32[gr * 128 + n] = acc[nt][j] + scj[j] * svn + bn;
            }
        }
    }
}

// ---------------- launch ----------------

extern "C" void kernel_launch(void* const* d_in, const int* in_sizes, int n_in,
                              void* d_out, int out_size, void* d_ws, size_t ws_size,
                              hipStream_t stream) {
    const float* x     = (const float*)d_in[0];   // [NN, 64]
    const int*   ei    = (const int*)d_in[1];     // [2, E]
    const float* W1    = (const float*)d_in[2];
    const float* b1    = (const float*)d_in[3];
    const float* gamma = (const float*)d_in[4];
    const float* beta  = (const float*)d_in[5];
    const float* W2    = (const float*)d_in[6];
    const float* b2    = (const float*)d_in[7];
    float* out = (float*)d_out;                   // [NN, 128]

    const int E = in_sizes[1] / 2;
    const int* row = ei;
    const int* col = ei + E;
    const int binBlks = (E + TILE - 1) / TILE;

    // workspace layout (4-byte units)
    int*   bcur    = (int*)d_ws;                      // 8192
    int*   cnt     = bcur + 8192;                     // 102400
    int*   start   = cnt + 102400;                    // 102400
    float* dis     = (float*)(start + 102400);        // 102400
    float* stats   = dis + 102400;                    // NREP*256 = 4096
    float* sv      = stats + 4096;                    // 128 (pad to 1024)
    float* sumcoef = stats + 5120;                    // 102400
    _Float16* wp1  = (_Float16*)(sumcoef + 102400);   // 8192 halves (4096 ints)
    _Float16* wp12 = wp1 + 8192;                      // 8192 halves (4096 ints)
    int*   rows    = (int*)(wp12 + 8192);             // NB*CAP
    int*   Rbase   = rows + NB * CAP;
    _Float16* xh   = (_Float16*)Rbase;                // NN*64 f16 (3,276,800 ints region)
    int*   ebuf    = Rbase + 3276800;                 // NB*CAP ints
    _Float16* y    = (_Float16*)(ebuf + NB * CAP);    // NN*64 f16
    _Float16* z    = xh;                              // overlay: xh dead after first agg

    // 1. prep0 (zero + pack W1), fused bin+cvt, CSR finalize
    k_prep0<<<ZERO_BLKS + PACK1_BLKS, 256, 0, stream>>>(bcur, stats, W1, wp1);
    k_binc<<<binBlks + CVT_BLKS, 256, 0, stream>>>(row, col, bcur, ebuf, E,
                                                   binBlks, x, xh);
    k_csr<<<NB, 256, 0, stream>>>(bcur, ebuf, rows, start, cnt, dis);

    // 2. y = agg(xh) (+ sumcoef); BN stats from y@W1+b1 (nothing materialized)
    k_aggy<<<AGG_BLKS, 256, 0, stream>>>(xh, rows, start, cnt, dis, y, sumcoef);
    k_mgemm<false><<<(NN + 63) / 64, 256, 0, stream>>>(y, wp1, b1, nullptr,
                                                       nullptr, nullptr, stats);

    // 3. fused: z = agg(y) | BN finalize + W12 pack + sv
    k_aggz<<<AGG_BLKS + 33, 256, 0, stream>>>(y, rows, start, cnt, dis, z,
                                              stats, gamma, beta, b1, W1, W2,
                                              wp12, sv);

    // 4. out = z @ W12 + sumcoef*sv + b2
    k_mgemm<true><<<(NN + 63) / 64, 256, 0, stream>>>(z, wp12, b2, sv,
                                                      sumcoef, out, nullptr);
}

// Round 11
// 147.533 us; speedup vs baseline: 1.6594x; 1.0058x over previous
//
#include <hip/hip_runtime.h>

#define NN 100000
#define BN_EPS 1e-5f
#define NBK 782         // buckets = ceil(NN/128), bucket b owns cols [b*128, b*128+128)
#define CAP 2560        // per-bucket edge capacity (mean 2046, +11 sigma)
#define TILE 4096       // edges per k_bin block

#define NREP 16         // BN-stats replicas (atomic-contention spreading)
#define CVT_BLKS 6250   // NN*16 float4s / 256
#define AGG_BLKS 6250   // NN/16
#define ZERO_BLKS 80    // 16384 bcur + NREP*256 stats = 20480 ints
#define PACK1_BLKS 32   // 64*128 / 256

typedef __attribute__((ext_vector_type(4))) _Float16 half4;
typedef __attribute__((ext_vector_type(8))) _Float16 half8;
typedef __attribute__((ext_vector_type(4))) float f32x4;

// ---------------- prep0: zero counters/stats | pack W1 ----------------
// wp flat idx i = ((kt*8 + nt)*64 + l)*8 + j  ->  W[kt*32 + (l>>4)*8 + j][nt*16 + (l&15)]

__global__ __launch_bounds__(256) void k_prep0(int* __restrict__ bcur,
                                               float* __restrict__ stats,
                                               const float* __restrict__ W1,
                                               _Float16* __restrict__ wp1) {
    const int b = blockIdx.x;
    const int t = threadIdx.x;
    if (b < ZERO_BLKS) {
        int i = b * 256 + t;
        if (i < 16384) bcur[i] = 0;
        else stats[i - 16384] = 0.f;             // NREP*256 = 4096
    } else {
        int i = (b - ZERO_BLKS) * 256 + t;       // < 8192
        int j = i & 7, l = (i >> 3) & 63, nt = (i >> 9) & 7, kt = i >> 12;
        int k = kt * 32 + ((l >> 4) << 3) + j;
        int n = nt * 16 + (l & 15);
        wp1[i] = (_Float16)W1[k * 128 + n];
    }
}

// ---------------- pass 1 (fused): bin edges by col>>7 | x->f16 convert ----------------

__global__ __launch_bounds__(256) void k_binc(const int* __restrict__ row,
                                              const int* __restrict__ col,
                                              int* __restrict__ bcur,   // NBK counters, stride 16
                                              int* __restrict__ ebuf,   // NBK*CAP packed edges
                                              int E, int binBlks,
                                              const float* __restrict__ x,
                                              _Float16* __restrict__ xh) {
    __shared__ int hist[1024];
    __shared__ int excl[1024];
    __shared__ int cur[1024];
    __shared__ int gbase[1024];
    __shared__ int sc[256];
    __shared__ int staged[TILE];
    __shared__ unsigned short bkt[TILE];
    const int t = threadIdx.x;

    if (blockIdx.x >= binBlks) {
        // cvt role: convert 256 float4s of x to f16
        int i = (blockIdx.x - binBlks) * 256 + t;    // < NN*16 exactly
        float4 v = reinterpret_cast<const float4*>(x)[i];
        half4 o;
        o.x = (_Float16)v.x; o.y = (_Float16)v.y;
        o.z = (_Float16)v.z; o.w = (_Float16)v.w;
        reinterpret_cast<half4*>(xh)[i] = o;
        return;
    }

    const int base = blockIdx.x * TILE;
    const int nE = min(TILE, E - base);

    #pragma unroll
    for (int q = 0; q < 4; ++q) { hist[q * 256 + t] = 0; cur[q * 256 + t] = 0; }
    __syncthreads();

    int er[16], ec[16];
    #pragma unroll
    for (int k = 0; k < 16; ++k) {
        int idx = base + k * 256 + t;
        if (idx < E) {
            er[k] = row[idx];
            ec[k] = col[idx];
            atomicAdd(&hist[ec[k] >> 7], 1);
        } else {
            ec[k] = -1;
        }
    }
    __syncthreads();

    // exclusive scan of hist[1024]: 4 entries/thread pair-sum + Hillis-Steele
    int h0 = hist[4 * t], h1 = hist[4 * t + 1], h2 = hist[4 * t + 2], h3 = hist[4 * t + 3];
    int p = h0 + h1 + h2 + h3;
    sc[t] = p;
    __syncthreads();
    for (int off = 1; off < 256; off <<= 1) {
        int add = (t >= off) ? sc[t - off] : 0;
        __syncthreads();
        sc[t] += add;
        __syncthreads();
    }
    int e0 = sc[t] - p;
    excl[4 * t]     = e0;
    excl[4 * t + 1] = e0 + h0;
    excl[4 * t + 2] = e0 + h0 + h1;
    excl[4 * t + 3] = e0 + h0 + h1 + h2;
    __syncthreads();

    for (int b = t; b < NBK; b += 256) {
        int h = hist[b];
        gbase[b] = h ? atomicAdd(&bcur[b * 16], h) : 0;
    }

    #pragma unroll
    for (int k = 0; k < 16; ++k) {
        int c = ec[k];
        if (c < 0) continue;
        int b = c >> 7;
        int slot = excl[b] + atomicAdd(&cur[b], 1);
        staged[slot] = (er[k] << 7) | (c & 127);
        bkt[slot] = (unsigned short)b;
    }
    __syncthreads();

    for (int i = t; i < nE; i += 256) {
        int b = bkt[i];
        int off = gbase[b] + (i - excl[b]);
        if (off < CAP) ebuf[b * CAP + off] = staged[i];
    }
}

// ---------------- pass 2: per-bucket CSR finalize (128 cols/bucket) ----------------

__global__ __launch_bounds__(256) void k_csr(const int* __restrict__ bcur,
                                             const int* __restrict__ ebuf,
                                             int* __restrict__ rows,
                                             int* __restrict__ start,
                                             int* __restrict__ cnt,
                                             float* __restrict__ dis) {
    __shared__ int hist[128];
    __shared__ int lstart[128];
    __shared__ int cur[128];
    __shared__ int sc[256];
    const int b = blockIdx.x;
    const int t = threadIdx.x;
    const int fill = min(bcur[b * 16], CAP);

    if (t < 128) { hist[t] = 0; cur[t] = 0; }
    __syncthreads();

    int er[CAP / 256];                   // 10 regs
    #pragma unroll
    for (int k = 0; k < CAP / 256; ++k) {
        int i = k * 256 + t;
        if (i < fill) {
            er[k] = ebuf[b * CAP + i];
            atomicAdd(&hist[er[k] & 127], 1);
        }
    }
    __syncthreads();

    int v = (t < 128) ? hist[t] : 0;
    sc[t] = v;
    __syncthreads();
    for (int off = 1; off < 256; off <<= 1) {
        int add = (t >= off) ? sc[t - off] : 0;
        __syncthreads();
        sc[t] += add;
        __syncthreads();
    }
    if (t < 128) {
        lstart[t] = sc[t] - v;
        const int node = b * 128 + t;
        if (node < NN) {
            start[node] = b * CAP + (sc[t] - v);
            cnt[node] = v;
            dis[node] = rsqrtf((float)(v + 1));
        }
    }
    __syncthreads();

    #pragma unroll
    for (int k = 0; k < CAP / 256; ++k) {
        int i = k * 256 + t;
        if (i < fill) {
            int lc = er[k] & 127;
            int lpos = atomicAdd(&cur[lc], 1);
            rows[b * CAP + lstart[lc] + lpos] = er[k] >> 7;
        }
    }
}

// ---------------- pull aggregation body (F=64: L=16 lanes/node, 16 nodes/block) ----------------

__device__ __forceinline__ void fma_h4(float4& a, half4 v, float c) {
    a.x = fmaf((float)v.x, c, a.x);
    a.y = fmaf((float)v.y, c, a.y);
    a.z = fmaf((float)v.z, c, a.z);
    a.w = fmaf((float)v.w, c, a.w);
}

template<bool SUMC>
__device__ __forceinline__ void agg_body(int blk,
                                         const _Float16* __restrict__ xh,
                                         const int* __restrict__ rows,
                                         const int* __restrict__ start,
                                         const int* __restrict__ cnt,
                                         const float* __restrict__ dis,
                                         _Float16* __restrict__ agg,
                                         float* __restrict__ sumcoef) {
    constexpr int L = 16;
    const int t = threadIdx.x;
    const int g = t / L;
    const int fid = t % L;
    const int n = blk * 16 + g;
    if (n >= NN) return;
    const int s = start[n];
    const int c = cnt[n];
    const float dn = dis[n];
    const half4* X4 = reinterpret_cast<const half4*>(xh);
    half4 hv = X4[n * L + fid];
    const float dn2 = dn * dn;
    float4 acc = make_float4(dn2 * (float)hv.x, dn2 * (float)hv.y,
                             dn2 * (float)hv.z, dn2 * (float)hv.w);
    float sd = 0.f;
    const int* rp = rows + s;
    int k = 0;
    for (; k + 4 <= c; k += 4) {
        int r0 = rp[k], r1 = rp[k + 1], r2 = rp[k + 2], r3 = rp[k + 3];
        float d0 = dis[r0], d1 = dis[r1], d2 = dis[r2], d3 = dis[r3];
        half4 v0 = X4[r0 * L + fid];
        half4 v1 = X4[r1 * L + fid];
        half4 v2 = X4[r2 * L + fid];
        half4 v3 = X4[r3 * L + fid];
        fma_h4(acc, v0, d0 * dn);
        fma_h4(acc, v1, d1 * dn);
        fma_h4(acc, v2, d2 * dn);
        fma_h4(acc, v3, d3 * dn);
        sd += (d0 + d1) + (d2 + d3);
    }
    for (; k < c; ++k) {
        int r = rp[k];
        float dr = dis[r];
        half4 v = X4[r * L + fid];
        fma_h4(acc, v, dr * dn);
        sd += dr;
    }
    half4 o;
    o.x = (_Float16)acc.x; o.y = (_Float16)acc.y;
    o.z = (_Float16)acc.z; o.w = (_Float16)acc.w;
    reinterpret_cast<half4*>(agg)[n * L + fid] = o;
    if (SUMC && fid == 0) sumcoef[n] = dn * sd + dn2;
}

// ---------------- layer-2 prep body: rep-sum + BN finalize + W12 + sv ----------------

__device__ __forceinline__ void l2prep_body(int bb,
                                            const float* __restrict__ stats,
                                            const float* __restrict__ gamma,
                                            const float* __restrict__ beta,
                                            const float* __restrict__ b1,
                                            const float* __restrict__ W1,
                                            const float* __restrict__ W2,
                                            _Float16* __restrict__ wp12,
                                            float* __restrict__ sv) {
    __shared__ float s_[128];
    __shared__ float f2_[128];
    const int t = threadIdx.x;
    if (t < 128) {
        float sum = 0.f, sum2 = 0.f;
        #pragma unroll
        for (int r = 0; r < NREP; ++r) {
            sum  += stats[r * 256 + t];
            sum2 += stats[r * 256 + 128 + t];
        }
        const float n = (float)NN;
        float mean = sum / n;
        float var = sum2 / n - mean * mean;
        float sc = gamma[t] * rsqrtf(var + BN_EPS);
        s_[t] = sc;
        f2_[t] = b1[t] * sc + (beta[t] - mean * sc);
    }
    __syncthreads();
    if (bb < 32) {
        int i = bb * 256 + t;                // 8192 packed W12 entries (K=64)
        int j = i & 7, l = (i >> 3) & 63, nt = (i >> 9) & 7, kt = i >> 12;
        int kk = kt * 32 + ((l >> 4) << 3) + j;     // 0..63
        int nn = nt * 16 + (l & 15);                 // 0..127
        float acc = 0.f;
        #pragma unroll 8
        for (int m = 0; m < 128; ++m)
            acc = fmaf(W1[kk * 128 + m] * s_[m], W2[m * 128 + nn], acc);
        wp12[i] = (_Float16)acc;
    } else if (t < 128) {
        float acc = 0.f;
        for (int k = 0; k < 128; ++k) acc = fmaf(f2_[k], W2[k * 128 + t], acc);
        sv[t] = acc;
    }
}

// ---------------- standalone agg (y pass, with sumcoef) ----------------

__global__ __launch_bounds__(256) void k_aggy(const _Float16* __restrict__ xh,
                                              const int* __restrict__ rows,
                                              const int* __restrict__ start,
                                              const int* __restrict__ cnt,
                                              const float* __restrict__ dis,
                                              _Float16* __restrict__ agg,
                                              float* __restrict__ sumcoef) {
    agg_body<true>(blockIdx.x, xh, rows, start, cnt, dis, agg, sumcoef);
}

// ---------------- fused: agg (z pass) | l2prep ----------------

__global__ __launch_bounds__(256) void k_aggz(const _Float16* __restrict__ y,
                                              const int* __restrict__ rows,
                                              const int* __restrict__ start,
                                              const int* __restrict__ cnt,
                                              const float* __restrict__ dis,
                                              _Float16* __restrict__ z,
                                              const float* __restrict__ stats,
                                              const float* __restrict__ gamma,
                                              const float* __restrict__ beta,
                                              const float* __restrict__ b1,
                                              const float* __restrict__ W1,
                                              const float* __restrict__ W2,
                                              _Float16* __restrict__ wp12,
                                              float* __restrict__ sv) {
    if (blockIdx.x < AGG_BLKS) {
        agg_body<false>(blockIdx.x, y, rows, start, cnt, dis, z, nullptr);
    } else {
        l2prep_body(blockIdx.x - AGG_BLKS, stats, gamma, beta, b1, W1, W2,
                    wp12, sv);
    }
}

// ---------------- MFMA GEMM (K=64): [NN,64] f16 @ packed W -> 128 cols ----------------
// FINAL=false: stats-only pass (h1 = y@W1 + b1, accumulate BN sums into replica).
// FINAL=true:  out32 = acc + sumcoef[row]*sv[n] + bias[n], LDS-transposed float4 store.

template<bool FINAL>
__global__ __launch_bounds__(256) void k_mgemm(const _Float16* __restrict__ A,
                                               const _Float16* __restrict__ Wp,
                                               const float* __restrict__ bias,
                                               const float* __restrict__ sv,
                                               const float* __restrict__ sumcoef,
                                               float* __restrict__ out32,
                                               float* __restrict__ stats) {
    const int t = threadIdx.x;
    const int wv = t >> 6;
    const int ln = t & 63;
    const int cgrp = ln >> 4;
    const int ncol = ln & 15;
    const int r0 = blockIdx.x * 64 + wv * 16;
    const int arow = min(r0 + ncol, NN - 1);

    f32x4 acc[8];
    #pragma unroll
    for (int nt = 0; nt < 8; ++nt) acc[nt] = {0.f, 0.f, 0.f, 0.f};

    const half8* Ap = reinterpret_cast<const half8*>(A + arow * 64 + cgrp * 8);
    const half8* Bp = reinterpret_cast<const half8*>(Wp);

    #pragma unroll
    for (int kt = 0; kt < 2; ++kt) {
        half8 a = Ap[kt * 4];
        #pragma unroll
        for (int nt = 0; nt < 8; ++nt) {
            half8 b = Bp[(kt * 8 + nt) * 64 + ln];
            acc[nt] = __builtin_amdgcn_mfma_f32_16x16x32_f16(a, b, acc[nt], 0, 0, 0);
        }
    }

    if constexpr (!FINAL) {
        __shared__ float ls[4][128];
        __shared__ float ls2[4][128];
        #pragma unroll
        for (int nt = 0; nt < 8; ++nt) {
            const int n = nt * 16 + ncol;
            const float bn = bias[n];
            float s = 0.f, s2 = 0.f;
            #pragma unroll
            for (int j = 0; j < 4; ++j) {
                int gr = r0 + cgrp * 4 + j;
                float v = acc[nt][j] + bn;
                if (gr < NN) {
                    s += v;
                    s2 += v * v;
                }
            }
            s  += __shfl_xor(s, 16);  s  += __shfl_xor(s, 32);
            s2 += __shfl_xor(s2, 16); s2 += __shfl_xor(s2, 32);
            if (ln < 16) { ls[wv][n] = s; ls2[wv][n] = s2; }
        }
        __syncthreads();
        float* rep = stats + (blockIdx.x & (NREP - 1)) * 256;
        if (t < 128) {
            atomicAdd(&rep[t], ls[0][t] + ls[1][t] + ls[2][t] + ls[3][t]);
        } else {
            int u = t - 128;
            atomicAdd(&rep[128 + u], ls2[0][u] + ls2[1][u] + ls2[2][u] + ls2[3][u]);
        }
    } else {
        __shared__ float st[4][16][132];     // per-wave 16x128 tile, pad 4
        float scj[4];
        #pragma unroll
        for (int j = 0; j < 4; ++j) scj[j] = sumcoef[min(r0 + cgrp * 4 + j, NN - 1)];
        #pragma unroll
        for (int nt = 0; nt < 8; ++nt) {
            const int n = nt * 16 + ncol;
            const float svn = sv[n];
            const float bn = bias[n];
            #pragma unroll
            for (int j = 0; j < 4; ++j)
                st[wv][cgrp * 4 + j][n] = acc[nt][j] + scj[j] * svn + bn;
        }
        __syncthreads();
        #pragma unroll
        for (int i = 0; i < 8; ++i) {
            int idx = i * 64 + ln;           // 0..511
            int rr = idx >> 5;               // 0..15
            int c4 = idx & 31;               // 0..31
            int gr = r0 + rr;
            if (gr < NN) {
                float4 v = *reinterpret_cast<float4*>(&st[wv][rr][c4 * 4]);
                *reinterpret_cast<float4*>(&out32[gr * 128 + c4 * 4]) = v;
            }
        }
    }
}

// ---------------- launch ----------------

extern "C" void kernel_launch(void* const* d_in, const int* in_sizes, int n_in,
                              void* d_out, int out_size, void* d_ws, size_t ws_size,
                              hipStream_t stream) {
    const float* x     = (const float*)d_in[0];   // [NN, 64]
    const int*   ei    = (const int*)d_in[1];     // [2, E]
    const float* W1    = (const float*)d_in[2];
    const float* b1    = (const float*)d_in[3];
    const float* gamma = (const float*)d_in[4];
    const float* beta  = (const float*)d_in[5];
    const float* W2    = (const float*)d_in[6];
    const float* b2    = (const float*)d_in[7];
    float* out = (float*)d_out;                   // [NN, 128]

    const int E = in_sizes[1] / 2;
    const int* row = ei;
    const int* col = ei + E;
    const int binBlks = (E + TILE - 1) / TILE;

    // workspace layout (4-byte units)
    int*   bcur    = (int*)d_ws;                      // 1024*16 = 16384
    int*   cnt     = bcur + 16384;                    // 102400
    int*   start   = cnt + 102400;                    // 102400
    float* dis     = (float*)(start + 102400);        // 102400
    float* stats   = dis + 102400;                    // NREP*256 = 4096
    float* sv      = stats + 4096;                    // 128 (pad to 1024)
    float* sumcoef = stats + 5120;                    // 102400
    _Float16* wp1  = (_Float16*)(sumcoef + 102400);   // 8192 halves (4096 ints)
    _Float16* wp12 = wp1 + 8192;                      // 8192 halves (4096 ints)
    int*   rows    = (int*)(wp12 + 8192);             // NBK*CAP = 2,001,920
    int*   Rbase   = rows + NBK * CAP;
    _Float16* xh   = (_Float16*)Rbase;                // NN*64 f16 (3,276,800 ints region)
    int*   ebuf    = Rbase + 3276800;                 // NBK*CAP ints
    _Float16* y    = (_Float16*)(ebuf + NBK * CAP);   // NN*64 f16
    _Float16* z    = xh;                              // overlay: xh dead after first agg

    // 1. prep0 (zero + pack W1), fused bin+cvt, CSR finalize
    k_prep0<<<ZERO_BLKS + PACK1_BLKS, 256, 0, stream>>>(bcur, stats, W1, wp1);
    k_binc<<<binBlks + CVT_BLKS, 256, 0, stream>>>(row, col, bcur, ebuf, E,
                                                   binBlks, x, xh);
    k_csr<<<NBK, 256, 0, stream>>>(bcur, ebuf, rows, start, cnt, dis);

    // 2. y = agg(xh) (+ sumcoef); BN stats from y@W1+b1 (nothing materialized)
    k_aggy<<<AGG_BLKS, 256, 0, stream>>>(xh, rows, start, cnt, dis, y, sumcoef);
    k_mgemm<false><<<(NN + 63) / 64, 256, 0, stream>>>(y, wp1, b1, nullptr,
                                                       nullptr, nullptr, stats);

    // 3. fused: z = agg(y) | BN finalize + W12 pack + sv
    k_aggz<<<AGG_BLKS + 33, 256, 0, stream>>>(y, rows, start, cnt, dis, z,
                                              stats, gamma, beta, b1, W1, W2,
                                              wp12, sv);

    // 4. out = z @ W12 + sumcoef*sv + b2 (LDS-transposed coalesced store)
    k_mgemm<true><<<(NN + 63) / 64, 256, 0, stream>>>(z, wp12, b2, sv,
                                                      sumcoef, out, nullptr);
}